// Round 1
// baseline (3080.824 us; speedup 1.0000x reference)
//
#include <hip/hip_runtime.h>
#include <math.h>

#define N_NODES 100000
#define N_EDGES 1600000
#define IN_F 256
#define OUT_F 128

// ---------------- degree histogram ----------------
__global__ void degree_kernel(const int* __restrict__ src,
                              const int* __restrict__ dst,
                              int* __restrict__ deg_out,
                              int* __restrict__ deg_in, int E) {
    int e = blockIdx.x * blockDim.x + threadIdx.x;
    if (e < E) {
        atomicAdd(&deg_out[src[e]], 1);
        atomicAdd(&deg_in[dst[e]], 1);
    }
}

// ---------------- deg -> rsqrt(clip(deg,1)) ----------------
__global__ void rs_kernel(const int* __restrict__ deg_out,
                          const int* __restrict__ deg_in,
                          float* __restrict__ rs_out,
                          float* __restrict__ rs_in, int N) {
    int n = blockIdx.x * blockDim.x + threadIdx.x;
    if (n < N) {
        int o = deg_out[n]; if (o < 1) o = 1;
        int i = deg_in[n];  if (i < 1) i = 1;
        rs_out[n] = rsqrtf((float)o);
        rs_in[n]  = rsqrtf((float)i);
    }
}

// ---------------- h = tanh((feat * rs_out[row]) @ W) ----------------
// 64 rows x 128 cols per block, 256 threads, BK=32 K-tile in LDS.
#define BM 64
#define BK 32
__global__ __launch_bounds__(256) void gemm_tanh_kernel(
        const float* __restrict__ feat, const float* __restrict__ W,
        const float* __restrict__ rs_out, float* __restrict__ h, int N) {
    __shared__ float As[BM][BK];     // 8 KB
    __shared__ float Bs[BK][OUT_F];  // 16 KB
    const int tid = threadIdx.x;
    const int row0 = blockIdx.x * BM;
    const int ty = tid >> 5;         // 0..7 -> 8 rows each
    const int tx = tid & 31;         // 0..31 -> cols tx+{0,32,64,96}

    float acc[8][4] = {};

    for (int k0 = 0; k0 < IN_F; k0 += BK) {
        // A tile: 64x32 floats = 512 float4, 2 per thread
        #pragma unroll
        for (int i = tid; i < BM * BK / 4; i += 256) {
            int r  = i / (BK / 4);
            int kq = i % (BK / 4);
            int row = row0 + r;
            float4 v = make_float4(0.f, 0.f, 0.f, 0.f);
            if (row < N) {
                v = *(const float4*)&feat[(size_t)row * IN_F + k0 + kq * 4];
                float s = rs_out[row];
                v.x *= s; v.y *= s; v.z *= s; v.w *= s;
            }
            *(float4*)&As[r][kq * 4] = v;
        }
        // B tile: 32x128 floats = 1024 float4, 4 per thread
        #pragma unroll
        for (int i = tid; i < BK * OUT_F / 4; i += 256) {
            int r  = i / (OUT_F / 4);
            int cq = i % (OUT_F / 4);
            *(float4*)&Bs[r][cq * 4] = *(const float4*)&W[(size_t)(k0 + r) * OUT_F + cq * 4];
        }
        __syncthreads();
        #pragma unroll
        for (int kk = 0; kk < BK; ++kk) {
            float b0 = Bs[kk][tx];
            float b1 = Bs[kk][tx + 32];
            float b2 = Bs[kk][tx + 64];
            float b3 = Bs[kk][tx + 96];
            #pragma unroll
            for (int r = 0; r < 8; ++r) {
                float a = As[ty * 8 + r][kk];
                acc[r][0] += a * b0;
                acc[r][1] += a * b1;
                acc[r][2] += a * b2;
                acc[r][3] += a * b3;
            }
        }
        __syncthreads();
    }
    #pragma unroll
    for (int r = 0; r < 8; ++r) {
        int row = row0 + ty * 8 + r;
        if (row < N) {
            float* o = &h[(size_t)row * OUT_F];
            o[tx]      = tanhf(acc[r][0]);
            o[tx + 32] = tanhf(acc[r][1]);
            o[tx + 64] = tanhf(acc[r][2]);
            o[tx + 96] = tanhf(acc[r][3]);
        }
    }
}

// ---------------- edge scatter: out[dst] += h[src] * ew * rs_in[dst] ----------------
// 32 threads per edge, each handles 4 consecutive feats (float4 gather + 4 atomics)
__global__ void scatter_kernel(const float* __restrict__ h,
                               const float* __restrict__ ew,
                               const int* __restrict__ src,
                               const int* __restrict__ dst,
                               const float* __restrict__ rs_in,
                               float* __restrict__ out, int E) {
    int idx = blockIdx.x * blockDim.x + threadIdx.x;   // < E*32 = 51.2M
    if (idx >= E * 32) return;
    int e = idx >> 5;
    int j = idx & 31;
    int s = src[e];
    int d = dst[e];
    float w = ew[e] * rs_in[d];
    float4 v = *(const float4*)&h[(size_t)s * OUT_F + j * 4];
    float* o = &out[(size_t)d * OUT_F + j * 4];
    atomicAdd(o + 0, v.x * w);
    atomicAdd(o + 1, v.y * w);
    atomicAdd(o + 2, v.z * w);
    atomicAdd(o + 3, v.w * w);
}

extern "C" void kernel_launch(void* const* d_in, const int* in_sizes, int n_in,
                              void* d_out, int out_size, void* d_ws, size_t ws_size,
                              hipStream_t stream) {
    const float* feat   = (const float*)d_in[0];
    const float* weight = (const float*)d_in[1];
    const float* ew     = (const float*)d_in[2];
    const int*   src    = (const int*)d_in[3];
    const int*   dst    = (const int*)d_in[4];
    float* out = (float*)d_out;

    // workspace layout (16B aligned)
    char* ws = (char*)d_ws;
    int*   deg_out = (int*)(ws);                       // 400000 B
    int*   deg_in  = (int*)(ws + 400000);              // 400000 B
    float* rs_out  = (float*)(ws + 800000);            // 400000 B
    float* rs_in   = (float*)(ws + 1200000);           // 400000 B
    float* h       = (float*)(ws + 1600000);           // 51.2 MB

    // zero degree buffers + output accumulator
    hipMemsetAsync(deg_out, 0, 2 * 400000, stream);
    hipMemsetAsync(out, 0, (size_t)out_size * sizeof(float), stream);

    degree_kernel<<<(N_EDGES + 255) / 256, 256, 0, stream>>>(src, dst, deg_out, deg_in, N_EDGES);
    rs_kernel<<<(N_NODES + 255) / 256, 256, 0, stream>>>(deg_out, deg_in, rs_out, rs_in, N_NODES);
    gemm_tanh_kernel<<<(N_NODES + BM - 1) / BM, 256, 0, stream>>>(feat, weight, rs_out, h, N_NODES);
    {
        int total = N_EDGES * 32;
        scatter_kernel<<<(total + 255) / 256, 256, 0, stream>>>(h, ew, src, dst, rs_in, out, N_EDGES);
    }
}

// Round 2
// 827.138 us; speedup vs baseline: 3.7247x; 3.7247x over previous
//
#include <hip/hip_runtime.h>
#include <math.h>

#define N_NODES 100000
#define N_EDGES 1600000
#define IN_F 256
#define OUT_F 128

// ---------------- degree histogram ----------------
__global__ void degree_kernel(const int* __restrict__ src,
                              const int* __restrict__ dst,
                              int* __restrict__ deg_out,
                              int* __restrict__ deg_in, int E) {
    int e = blockIdx.x * blockDim.x + threadIdx.x;
    if (e < E) {
        atomicAdd(&deg_out[src[e]], 1);
        atomicAdd(&deg_in[dst[e]], 1);
    }
}

// ---------------- single-block exclusive scan of deg_in -> row_ptr ----------------
// 1024 threads, 4 elements/thread/tile (4096 per tile, ~25 tiles for 100k)
__global__ __launch_bounds__(1024) void scan_kernel(const int* __restrict__ deg,
                                                    int* __restrict__ row_ptr, int N) {
    __shared__ int tmp[1024];
    int base = 0;
    for (int t0 = 0; t0 < N; t0 += 4096) {
        int i0 = t0 + threadIdx.x * 4;
        int v[4];
        #pragma unroll
        for (int j = 0; j < 4; ++j) v[j] = (i0 + j < N) ? deg[i0 + j] : 0;
        int s = v[0] + v[1] + v[2] + v[3];
        tmp[threadIdx.x] = s;
        __syncthreads();
        int x = s;
        for (int off = 1; off < 1024; off <<= 1) {
            int y = (threadIdx.x >= off) ? tmp[threadIdx.x - off] : 0;
            __syncthreads();
            x += y;
            tmp[threadIdx.x] = x;
            __syncthreads();
        }
        int excl = base + x - s;
        #pragma unroll
        for (int j = 0; j < 4; ++j) {
            if (i0 + j < N) row_ptr[i0 + j] = excl;
            excl += v[j];
        }
        base += tmp[1023];
        __syncthreads();
    }
    if (threadIdx.x == 0) row_ptr[N] = base;
}

// ---------------- counting-sort fill: dst-grouped edge id permutation ----------------
__global__ void fill_kernel(const int* __restrict__ dst,
                            const int* __restrict__ row_ptr,
                            int* __restrict__ ctr,
                            int* __restrict__ e_id, int E) {
    int e = blockIdx.x * blockDim.x + threadIdx.x;
    if (e < E) {
        int d = dst[e];
        int p = row_ptr[d] + atomicAdd(&ctr[d], 1);
        e_id[p] = e;
    }
}

// ---------------- h = tanh((feat * rsqrt(out_deg)) @ W) ----------------
#define BM 64
#define BK 32
__global__ __launch_bounds__(256) void gemm_tanh_kernel(
        const float* __restrict__ feat, const float* __restrict__ W,
        const int* __restrict__ deg_out, float* __restrict__ h, int N) {
    __shared__ float As[BM][BK];     // 8 KB
    __shared__ float Bs[BK][OUT_F];  // 16 KB
    const int tid = threadIdx.x;
    const int row0 = blockIdx.x * BM;
    const int ty = tid >> 5;
    const int tx = tid & 31;

    float acc[8][4] = {};

    for (int k0 = 0; k0 < IN_F; k0 += BK) {
        #pragma unroll
        for (int i = tid; i < BM * BK / 4; i += 256) {
            int r  = i / (BK / 4);
            int kq = i % (BK / 4);
            int row = row0 + r;
            float4 v = make_float4(0.f, 0.f, 0.f, 0.f);
            if (row < N) {
                v = *(const float4*)&feat[(size_t)row * IN_F + k0 + kq * 4];
                int dg = deg_out[row]; if (dg < 1) dg = 1;
                float s = rsqrtf((float)dg);
                v.x *= s; v.y *= s; v.z *= s; v.w *= s;
            }
            *(float4*)&As[r][kq * 4] = v;
        }
        #pragma unroll
        for (int i = tid; i < BK * OUT_F / 4; i += 256) {
            int r  = i / (OUT_F / 4);
            int cq = i % (OUT_F / 4);
            *(float4*)&Bs[r][cq * 4] = *(const float4*)&W[(size_t)(k0 + r) * OUT_F + cq * 4];
        }
        __syncthreads();
        #pragma unroll
        for (int kk = 0; kk < BK; ++kk) {
            float b0 = Bs[kk][tx];
            float b1 = Bs[kk][tx + 32];
            float b2 = Bs[kk][tx + 64];
            float b3 = Bs[kk][tx + 96];
            #pragma unroll
            for (int r = 0; r < 8; ++r) {
                float a = As[ty * 8 + r][kk];
                acc[r][0] += a * b0;
                acc[r][1] += a * b1;
                acc[r][2] += a * b2;
                acc[r][3] += a * b3;
            }
        }
        __syncthreads();
    }
    #pragma unroll
    for (int r = 0; r < 8; ++r) {
        int row = row0 + ty * 8 + r;
        if (row < N) {
            float* o = &h[(size_t)row * OUT_F];
            o[tx]      = tanhf(acc[r][0]);
            o[tx + 32] = tanhf(acc[r][1]);
            o[tx + 64] = tanhf(acc[r][2]);
            o[tx + 96] = tanhf(acc[r][3]);
        }
    }
}

// ---------------- gather: one wave per dst node ----------------
// out[n] = rsqrt(in_deg[n]) * sum_{e: dst(e)=n} h[src(e)] * ew[e]
__global__ __launch_bounds__(256) void gather_kernel(
        const float* __restrict__ h, const float* __restrict__ ew,
        const int* __restrict__ src, const int* __restrict__ e_id,
        const int* __restrict__ row_ptr, float* __restrict__ out, int N) {
    int wave = threadIdx.x >> 6;
    int lane = threadIdx.x & 63;
    int node = blockIdx.x * 4 + wave;
    if (node >= N) return;
    int lo = row_ptr[node];
    int hi = row_ptr[node + 1];
    float ax = 0.f, ay = 0.f;
    for (int j = lo; j < hi; ++j) {
        int e = e_id[j];
        int s = src[e];
        float w = ew[e];
        float2 v = *(const float2*)&h[(size_t)s * OUT_F + lane * 2];
        ax += v.x * w;
        ay += v.y * w;
    }
    int deg = hi - lo; if (deg < 1) deg = 1;
    float rs = rsqrtf((float)deg);
    float2 r = make_float2(ax * rs, ay * rs);
    *(float2*)&out[(size_t)node * OUT_F + lane * 2] = r;
}

extern "C" void kernel_launch(void* const* d_in, const int* in_sizes, int n_in,
                              void* d_out, int out_size, void* d_ws, size_t ws_size,
                              hipStream_t stream) {
    const float* feat   = (const float*)d_in[0];
    const float* weight = (const float*)d_in[1];
    const float* ew     = (const float*)d_in[2];
    const int*   src    = (const int*)d_in[3];
    const int*   dst    = (const int*)d_in[4];
    float* out = (float*)d_out;

    // workspace layout
    char* ws = (char*)d_ws;
    int*   deg_out = (int*)(ws);                 // 400,000 B
    int*   deg_in  = (int*)(ws + 400000);        // 400,000 B
    int*   ctr     = (int*)(ws + 800000);        // 400,000 B
    int*   row_ptr = (int*)(ws + 1200000);       // 400,004 B
    int*   e_id    = (int*)(ws + 1600016);       // 6,400,000 B
    float* h       = (float*)(ws + 8000016);     // 51,200,000 B  (16B aligned)

    // zero deg_out, deg_in, ctr in one shot
    hipMemsetAsync(deg_out, 0, 1200000, stream);

    degree_kernel<<<(N_EDGES + 255) / 256, 256, 0, stream>>>(src, dst, deg_out, deg_in, N_EDGES);
    scan_kernel<<<1, 1024, 0, stream>>>(deg_in, row_ptr, N_NODES);
    fill_kernel<<<(N_EDGES + 255) / 256, 256, 0, stream>>>(dst, row_ptr, ctr, e_id, N_EDGES);
    gemm_tanh_kernel<<<(N_NODES + BM - 1) / BM, 256, 0, stream>>>(feat, weight, deg_out, h, N_NODES);
    gather_kernel<<<(N_NODES + 3) / 4, 256, 0, stream>>>(h, ew, src, e_id, row_ptr, out, N_NODES);
}

// Round 3
// 581.050 us; speedup vs baseline: 5.3022x; 1.4235x over previous
//
#include <hip/hip_runtime.h>
#include <hip/hip_fp16.h>
#include <math.h>

#define N_NODES 100000
#define N_EDGES 1600000
#define IN_F 256
#define OUT_F 128
#define SCAN_TPB 256
#define SCAN_EPB 1024   // elems per block in scan (4/thread)

// ---------------- degree histogram ----------------
__global__ void degree_kernel(const int* __restrict__ src,
                              const int* __restrict__ dst,
                              int* __restrict__ deg_out,
                              int* __restrict__ deg_in, int E) {
    int e = blockIdx.x * blockDim.x + threadIdx.x;
    if (e < E) {
        atomicAdd(&deg_out[src[e]], 1);
        atomicAdd(&deg_in[dst[e]], 1);
    }
}

// ---------------- 3-kernel multi-block exclusive scan of deg_in ----------------
__global__ __launch_bounds__(SCAN_TPB) void scan_part1(const int* __restrict__ deg,
                                                       int* __restrict__ partials, int N) {
    __shared__ int tmp[SCAN_TPB];
    int t = threadIdx.x;
    int i0 = blockIdx.x * SCAN_EPB + t * 4;
    int s = 0;
    #pragma unroll
    for (int j = 0; j < 4; ++j) s += (i0 + j < N) ? deg[i0 + j] : 0;
    tmp[t] = s;
    __syncthreads();
    for (int off = SCAN_TPB / 2; off > 0; off >>= 1) {
        if (t < off) tmp[t] += tmp[t + off];
        __syncthreads();
    }
    if (t == 0) partials[blockIdx.x] = tmp[0];
}

__global__ __launch_bounds__(128) void scan_part2(const int* __restrict__ partials,
                                                  int* __restrict__ bases, int nb) {
    __shared__ int tmp[128];
    int t = threadIdx.x;
    int v = (t < nb) ? partials[t] : 0;
    tmp[t] = v;
    __syncthreads();
    int x = v;
    for (int off = 1; off < 128; off <<= 1) {
        int y = (t >= off) ? tmp[t - off] : 0;
        __syncthreads();
        x += y;
        tmp[t] = x;
        __syncthreads();
    }
    if (t < nb) bases[t] = x - v;   // exclusive
}

__global__ __launch_bounds__(SCAN_TPB) void scan_part3(const int* __restrict__ deg,
                                                       const int* __restrict__ bases,
                                                       int* __restrict__ row_ptr, int N) {
    __shared__ int tmp[SCAN_TPB];
    int t = threadIdx.x;
    int i0 = blockIdx.x * SCAN_EPB + t * 4;
    int v[4];
    int s = 0;
    #pragma unroll
    for (int j = 0; j < 4; ++j) { v[j] = (i0 + j < N) ? deg[i0 + j] : 0; s += v[j]; }
    tmp[t] = s;
    __syncthreads();
    int x = s;
    for (int off = 1; off < SCAN_TPB; off <<= 1) {
        int y = (t >= off) ? tmp[t - off] : 0;
        __syncthreads();
        x += y;
        tmp[t] = x;
        __syncthreads();
    }
    int excl = bases[blockIdx.x] + x - s;
    #pragma unroll
    for (int j = 0; j < 4; ++j) {
        if (i0 + j < N) row_ptr[i0 + j] = excl;
        excl += v[j];
    }
    // last element's owner writes the total
    if (blockIdx.x == gridDim.x - 1 && t == SCAN_TPB - 1) row_ptr[N] = bases[blockIdx.x] + x;
}

// ---------------- counting-sort fill: dst-grouped packed (src, ew) ----------------
__global__ void fill_kernel(const int* __restrict__ src,
                            const int* __restrict__ dst,
                            const float* __restrict__ ew,
                            const int* __restrict__ row_ptr,
                            int* __restrict__ ctr,
                            int2* __restrict__ ed, int E) {
    int e = blockIdx.x * blockDim.x + threadIdx.x;
    if (e < E) {
        int d = dst[e];
        int p = row_ptr[d] + atomicAdd(&ctr[d], 1);
        ed[p] = make_int2(src[e], __float_as_int(ew[e]));
    }
}

// ---------------- h = tanh((feat * rsqrt(out_deg)) @ W), fp16 output ----------------
#define BM 64
#define BK 32
__global__ __launch_bounds__(256) void gemm_tanh_kernel(
        const float* __restrict__ feat, const float* __restrict__ W,
        const int* __restrict__ deg_out, __half* __restrict__ h, int N) {
    __shared__ float As[BM][BK];     // 8 KB
    __shared__ float Bs[BK][OUT_F];  // 16 KB
    const int tid = threadIdx.x;
    const int row0 = blockIdx.x * BM;
    const int ty = tid >> 5;
    const int tx = tid & 31;

    float acc[8][4] = {};

    for (int k0 = 0; k0 < IN_F; k0 += BK) {
        #pragma unroll
        for (int i = tid; i < BM * BK / 4; i += 256) {
            int r  = i / (BK / 4);
            int kq = i % (BK / 4);
            int row = row0 + r;
            float4 v = make_float4(0.f, 0.f, 0.f, 0.f);
            if (row < N) {
                v = *(const float4*)&feat[(size_t)row * IN_F + k0 + kq * 4];
                int dg = deg_out[row]; if (dg < 1) dg = 1;
                float s = rsqrtf((float)dg);
                v.x *= s; v.y *= s; v.z *= s; v.w *= s;
            }
            *(float4*)&As[r][kq * 4] = v;
        }
        #pragma unroll
        for (int i = tid; i < BK * OUT_F / 4; i += 256) {
            int r  = i / (OUT_F / 4);
            int cq = i % (OUT_F / 4);
            *(float4*)&Bs[r][cq * 4] = *(const float4*)&W[(size_t)(k0 + r) * OUT_F + cq * 4];
        }
        __syncthreads();
        #pragma unroll
        for (int kk = 0; kk < BK; ++kk) {
            float b0 = Bs[kk][tx];
            float b1 = Bs[kk][tx + 32];
            float b2 = Bs[kk][tx + 64];
            float b3 = Bs[kk][tx + 96];
            #pragma unroll
            for (int r = 0; r < 8; ++r) {
                float a = As[ty * 8 + r][kk];
                acc[r][0] += a * b0;
                acc[r][1] += a * b1;
                acc[r][2] += a * b2;
                acc[r][3] += a * b3;
            }
        }
        __syncthreads();
    }
    #pragma unroll
    for (int r = 0; r < 8; ++r) {
        int row = row0 + ty * 8 + r;
        if (row < N) {
            __half* o = &h[(size_t)row * OUT_F];
            o[tx]      = __float2half(tanhf(acc[r][0]));
            o[tx + 32] = __float2half(tanhf(acc[r][1]));
            o[tx + 64] = __float2half(tanhf(acc[r][2]));
            o[tx + 96] = __float2half(tanhf(acc[r][3]));
        }
    }
}

// ---------------- gather: one wave per dst node, 2 edges/instr, unroll 2 ----------------
__global__ __launch_bounds__(256) void gather_kernel(
        const __half* __restrict__ h, const int2* __restrict__ ed,
        const int* __restrict__ row_ptr, float* __restrict__ out, int N) {
    int wave = threadIdx.x >> 6;
    int lane = threadIdx.x & 63;
    int node = blockIdx.x * 4 + wave;
    if (node >= N) return;
    int lo = row_ptr[node];
    int hi = row_ptr[node + 1];
    int p = lane >> 5;       // which edge of the pair
    int c = lane & 31;       // feature quad: feats 4c..4c+3
    float4 acc0 = make_float4(0.f, 0.f, 0.f, 0.f);
    float4 acc1 = make_float4(0.f, 0.f, 0.f, 0.f);
    for (int j = lo; j < hi; j += 4) {
        int ja = j + p;
        int jb = j + 2 + p;
        int2 ea = (ja < hi) ? ed[ja] : make_int2(0, 0);
        int2 eb = (jb < hi) ? ed[jb] : make_int2(0, 0);
        float wa = __int_as_float(ea.y);
        float wb = __int_as_float(eb.y);
        int2 ra = *(const int2*)&h[(size_t)ea.x * OUT_F + c * 4];
        int2 rb = *(const int2*)&h[(size_t)eb.x * OUT_F + c * 4];
        __half2 a0 = *(__half2*)&ra.x, a1 = *(__half2*)&ra.y;
        __half2 b0 = *(__half2*)&rb.x, b1 = *(__half2*)&rb.y;
        float2 fa0 = __half22float2(a0), fa1 = __half22float2(a1);
        float2 fb0 = __half22float2(b0), fb1 = __half22float2(b1);
        acc0.x += wa * fa0.x; acc0.y += wa * fa0.y;
        acc0.z += wa * fa1.x; acc0.w += wa * fa1.y;
        acc1.x += wb * fb0.x; acc1.y += wb * fb0.y;
        acc1.z += wb * fb1.x; acc1.w += wb * fb1.y;
    }
    acc0.x += acc1.x; acc0.y += acc1.y; acc0.z += acc1.z; acc0.w += acc1.w;
    acc0.x += __shfl_xor(acc0.x, 32);
    acc0.y += __shfl_xor(acc0.y, 32);
    acc0.z += __shfl_xor(acc0.z, 32);
    acc0.w += __shfl_xor(acc0.w, 32);
    if (p == 0) {
        int deg = hi - lo; if (deg < 1) deg = 1;
        float rs = rsqrtf((float)deg);
        *(float4*)&out[(size_t)node * OUT_F + c * 4] =
            make_float4(acc0.x * rs, acc0.y * rs, acc0.z * rs, acc0.w * rs);
    }
}

extern "C" void kernel_launch(void* const* d_in, const int* in_sizes, int n_in,
                              void* d_out, int out_size, void* d_ws, size_t ws_size,
                              hipStream_t stream) {
    const float* feat   = (const float*)d_in[0];
    const float* weight = (const float*)d_in[1];
    const float* ew     = (const float*)d_in[2];
    const int*   src    = (const int*)d_in[3];
    const int*   dst    = (const int*)d_in[4];
    float* out = (float*)d_out;

    // workspace layout
    char*  ws       = (char*)d_ws;
    int*   deg_out  = (int*)(ws);                  // 400,000 B
    int*   deg_in   = (int*)(ws + 400000);         // 400,000 B
    int*   ctr      = (int*)(ws + 800000);         // 400,000 B
    int*   row_ptr  = (int*)(ws + 1200000);        // 400,004 B
    int*   partials = (int*)(ws + 1600016);        // ~400 B
    int*   bases    = (int*)(ws + 1600448);        // ~400 B
    int2*  ed       = (int2*)(ws + 1600848);       // 12,800,000 B
    __half* h       = (__half*)(ws + 14400848);    // 25,600,000 B

    const int nb = (N_NODES + SCAN_EPB - 1) / SCAN_EPB;   // 98 scan blocks

    hipMemsetAsync(deg_out, 0, 1200000, stream);  // deg_out, deg_in, ctr

    degree_kernel<<<(N_EDGES + 255) / 256, 256, 0, stream>>>(src, dst, deg_out, deg_in, N_EDGES);
    scan_part1<<<nb, SCAN_TPB, 0, stream>>>(deg_in, partials, N_NODES);
    scan_part2<<<1, 128, 0, stream>>>(partials, bases, nb);
    scan_part3<<<nb, SCAN_TPB, 0, stream>>>(deg_in, bases, row_ptr, N_NODES);
    fill_kernel<<<(N_EDGES + 255) / 256, 256, 0, stream>>>(src, dst, ew, row_ptr, ctr, ed, N_EDGES);
    gemm_tanh_kernel<<<(N_NODES + BM - 1) / BM, 256, 0, stream>>>(feat, weight, deg_out, h, N_NODES);
    gather_kernel<<<(N_NODES + 3) / 4, 256, 0, stream>>>(h, ed, row_ptr, out, N_NODES);
}

// Round 4
// 536.454 us; speedup vs baseline: 5.7429x; 1.0831x over previous
//
#include <hip/hip_runtime.h>
#include <hip/hip_fp16.h>
#include <math.h>

#define N_NODES 100000
#define N_EDGES 1600000
#define IN_F 256
#define OUT_F 128
#define SCAN_TPB 256
#define SCAN_EPB 1024   // elems per block in scan (4/thread)

typedef _Float16 h8 __attribute__((ext_vector_type(8)));
typedef float f4 __attribute__((ext_vector_type(4)));

// ---------------- degree histogram ----------------
__global__ void degree_kernel(const int* __restrict__ src,
                              const int* __restrict__ dst,
                              int* __restrict__ deg_out,
                              int* __restrict__ deg_in, int E) {
    int e = blockIdx.x * blockDim.x + threadIdx.x;
    if (e < E) {
        atomicAdd(&deg_out[src[e]], 1);
        atomicAdd(&deg_in[dst[e]], 1);
    }
}

// ---------------- 3-kernel multi-block exclusive scan of deg_in ----------------
__global__ __launch_bounds__(SCAN_TPB) void scan_part1(const int* __restrict__ deg,
                                                       int* __restrict__ partials, int N) {
    __shared__ int tmp[SCAN_TPB];
    int t = threadIdx.x;
    int i0 = blockIdx.x * SCAN_EPB + t * 4;
    int s = 0;
    #pragma unroll
    for (int j = 0; j < 4; ++j) s += (i0 + j < N) ? deg[i0 + j] : 0;
    tmp[t] = s;
    __syncthreads();
    for (int off = SCAN_TPB / 2; off > 0; off >>= 1) {
        if (t < off) tmp[t] += tmp[t + off];
        __syncthreads();
    }
    if (t == 0) partials[blockIdx.x] = tmp[0];
}

__global__ __launch_bounds__(128) void scan_part2(const int* __restrict__ partials,
                                                  int* __restrict__ bases, int nb) {
    __shared__ int tmp[128];
    int t = threadIdx.x;
    int v = (t < nb) ? partials[t] : 0;
    tmp[t] = v;
    __syncthreads();
    int x = v;
    for (int off = 1; off < 128; off <<= 1) {
        int y = (t >= off) ? tmp[t - off] : 0;
        __syncthreads();
        x += y;
        tmp[t] = x;
        __syncthreads();
    }
    if (t < nb) bases[t] = x - v;   // exclusive
}

__global__ __launch_bounds__(SCAN_TPB) void scan_part3(const int* __restrict__ deg,
                                                       const int* __restrict__ bases,
                                                       int* __restrict__ row_ptr, int N) {
    __shared__ int tmp[SCAN_TPB];
    int t = threadIdx.x;
    int i0 = blockIdx.x * SCAN_EPB + t * 4;
    int v[4];
    int s = 0;
    #pragma unroll
    for (int j = 0; j < 4; ++j) { v[j] = (i0 + j < N) ? deg[i0 + j] : 0; s += v[j]; }
    tmp[t] = s;
    __syncthreads();
    int x = s;
    for (int off = 1; off < SCAN_TPB; off <<= 1) {
        int y = (t >= off) ? tmp[t - off] : 0;
        __syncthreads();
        x += y;
        tmp[t] = x;
        __syncthreads();
    }
    int excl = bases[blockIdx.x] + x - s;
    #pragma unroll
    for (int j = 0; j < 4; ++j) {
        if (i0 + j < N) row_ptr[i0 + j] = excl;
        excl += v[j];
    }
    if (blockIdx.x == gridDim.x - 1 && t == SCAN_TPB - 1) row_ptr[N] = bases[blockIdx.x] + x;
}

// ---------------- counting-sort fill: dst-grouped packed (src, ew) ----------------
__global__ void fill_kernel(const int* __restrict__ src,
                            const int* __restrict__ dst,
                            const float* __restrict__ ew,
                            const int* __restrict__ row_ptr,
                            int* __restrict__ ctr,
                            int2* __restrict__ ed, int E) {
    int e = blockIdx.x * blockDim.x + threadIdx.x;
    if (e < E) {
        int d = dst[e];
        int p = row_ptr[d] + atomicAdd(&ctr[d], 1);
        ed[p] = make_int2(src[e], __float_as_int(ew[e]));
    }
}

// ---------------- Wt[n][k] = (f16) W[k][n] ----------------
__global__ void wt_kernel(const float* __restrict__ W, _Float16* __restrict__ Wt) {
    int i = blockIdx.x * blockDim.x + threadIdx.x;   // 32768
    if (i < IN_F * OUT_F) {
        int n = i >> 8;           // 0..127
        int k = i & 255;          // 0..255
        Wt[i] = (_Float16)W[k * OUT_F + n];
    }
}

// ---------------- h = tanh((feat * rsqrt(out_deg)) @ W), f16 MFMA ----------------
// block = 4 waves; wave computes 16 rows x 128 cols via 8 16x16x32 tiles.
__global__ __launch_bounds__(256) void gemm_mfma_kernel(
        const float* __restrict__ feat, const _Float16* __restrict__ Wt,
        const int* __restrict__ deg_out, __half* __restrict__ h, int N) {
    const int wave = threadIdx.x >> 6;
    const int lane = threadIdx.x & 63;
    const int m = lane & 15;
    const int quad = lane >> 4;
    const int rowbase = blockIdx.x * 64 + wave * 16;
    const int arow = rowbase + m;            // A row this lane feeds
    const bool rowok = arow < N;

    float rs = 1.f;
    if (rowok) {
        int dg = deg_out[arow]; if (dg < 1) dg = 1;
        rs = rsqrtf((float)dg);
    }
    const float* ap = feat + (size_t)(rowok ? arow : 0) * IN_F + quad * 8;

    f4 acc[8];
    #pragma unroll
    for (int t = 0; t < 8; ++t) acc[t] = (f4){0.f, 0.f, 0.f, 0.f};

    #pragma unroll
    for (int k0 = 0; k0 < IN_F; k0 += 32) {
        float4 f0 = make_float4(0.f, 0.f, 0.f, 0.f);
        float4 f1 = make_float4(0.f, 0.f, 0.f, 0.f);
        if (rowok) {
            f0 = *(const float4*)(ap + k0);
            f1 = *(const float4*)(ap + k0 + 4);
        }
        h8 a;
        a[0] = (_Float16)(f0.x * rs); a[1] = (_Float16)(f0.y * rs);
        a[2] = (_Float16)(f0.z * rs); a[3] = (_Float16)(f0.w * rs);
        a[4] = (_Float16)(f1.x * rs); a[5] = (_Float16)(f1.y * rs);
        a[6] = (_Float16)(f1.z * rs); a[7] = (_Float16)(f1.w * rs);
        const int k = k0 + quad * 8;
        #pragma unroll
        for (int t = 0; t < 8; ++t) {
            h8 b = *(const h8*)&Wt[(size_t)(t * 16 + m) * IN_F + k];
            acc[t] = __builtin_amdgcn_mfma_f32_16x16x32_f16(a, b, acc[t], 0, 0, 0);
        }
    }

    // C layout: col = lane&15, row = quad*4 + reg
    const int crow0 = rowbase + quad * 4;
    #pragma unroll
    for (int t = 0; t < 8; ++t) {
        #pragma unroll
        for (int r = 0; r < 4; ++r) {
            int rr = crow0 + r;
            if (rr < N) h[(size_t)rr * OUT_F + t * 16 + m] = __float2half(tanhf(acc[t][r]));
        }
    }
}

// ---------------- gather: one wave per dst node, 2 edges/instr, unroll 2 ----------------
__global__ __launch_bounds__(256) void gather_kernel(
        const __half* __restrict__ h, const int2* __restrict__ ed,
        const int* __restrict__ row_ptr, float* __restrict__ out, int N) {
    int wave = threadIdx.x >> 6;
    int lane = threadIdx.x & 63;
    int node = blockIdx.x * 4 + wave;
    if (node >= N) return;
    int lo = row_ptr[node];
    int hi = row_ptr[node + 1];
    int p = lane >> 5;       // which edge of the pair
    int c = lane & 31;       // feature quad: feats 4c..4c+3
    float4 acc0 = make_float4(0.f, 0.f, 0.f, 0.f);
    float4 acc1 = make_float4(0.f, 0.f, 0.f, 0.f);
    for (int j = lo; j < hi; j += 4) {
        int ja = j + p;
        int jb = j + 2 + p;
        int2 ea = (ja < hi) ? ed[ja] : make_int2(0, 0);
        int2 eb = (jb < hi) ? ed[jb] : make_int2(0, 0);
        float wa = __int_as_float(ea.y);
        float wb = __int_as_float(eb.y);
        int2 ra = *(const int2*)&h[(size_t)ea.x * OUT_F + c * 4];
        int2 rb = *(const int2*)&h[(size_t)eb.x * OUT_F + c * 4];
        __half2 a0 = *(__half2*)&ra.x, a1 = *(__half2*)&ra.y;
        __half2 b0 = *(__half2*)&rb.x, b1 = *(__half2*)&rb.y;
        float2 fa0 = __half22float2(a0), fa1 = __half22float2(a1);
        float2 fb0 = __half22float2(b0), fb1 = __half22float2(b1);
        acc0.x += wa * fa0.x; acc0.y += wa * fa0.y;
        acc0.z += wa * fa1.x; acc0.w += wa * fa1.y;
        acc1.x += wb * fb0.x; acc1.y += wb * fb0.y;
        acc1.z += wb * fb1.x; acc1.w += wb * fb1.y;
    }
    acc0.x += acc1.x; acc0.y += acc1.y; acc0.z += acc1.z; acc0.w += acc1.w;
    acc0.x += __shfl_xor(acc0.x, 32);
    acc0.y += __shfl_xor(acc0.y, 32);
    acc0.z += __shfl_xor(acc0.z, 32);
    acc0.w += __shfl_xor(acc0.w, 32);
    if (p == 0) {
        int deg = hi - lo; if (deg < 1) deg = 1;
        float rs = rsqrtf((float)deg);
        *(float4*)&out[(size_t)node * OUT_F + c * 4] =
            make_float4(acc0.x * rs, acc0.y * rs, acc0.z * rs, acc0.w * rs);
    }
}

extern "C" void kernel_launch(void* const* d_in, const int* in_sizes, int n_in,
                              void* d_out, int out_size, void* d_ws, size_t ws_size,
                              hipStream_t stream) {
    const float* feat   = (const float*)d_in[0];
    const float* weight = (const float*)d_in[1];
    const float* ew     = (const float*)d_in[2];
    const int*   src    = (const int*)d_in[3];
    const int*   dst    = (const int*)d_in[4];
    float* out = (float*)d_out;

    // workspace layout
    char*   ws       = (char*)d_ws;
    int*    deg_out  = (int*)(ws);                  // 400,000 B
    int*    deg_in   = (int*)(ws + 400000);         // 400,000 B
    int*    ctr      = (int*)(ws + 800000);         // 400,000 B
    int*    row_ptr  = (int*)(ws + 1200000);        // 400,004 B
    int*    partials = (int*)(ws + 1600016);        // ~400 B
    int*    bases    = (int*)(ws + 1600448);        // ~400 B
    int2*   ed       = (int2*)(ws + 1600848);       // 12,800,000 B
    __half* h        = (__half*)(ws + 14400848);    // 25,600,000 B
    _Float16* Wt     = (_Float16*)(ws + 40000848);  // 65,536 B

    const int nb = (N_NODES + SCAN_EPB - 1) / SCAN_EPB;   // 98 scan blocks

    hipMemsetAsync(deg_out, 0, 1200000, stream);  // deg_out, deg_in, ctr

    degree_kernel<<<(N_EDGES + 255) / 256, 256, 0, stream>>>(src, dst, deg_out, deg_in, N_EDGES);
    scan_part1<<<nb, SCAN_TPB, 0, stream>>>(deg_in, partials, N_NODES);
    scan_part2<<<1, 128, 0, stream>>>(partials, bases, nb);
    scan_part3<<<nb, SCAN_TPB, 0, stream>>>(deg_in, bases, row_ptr, N_NODES);
    fill_kernel<<<(N_EDGES + 255) / 256, 256, 0, stream>>>(src, dst, ew, row_ptr, ctr, ed, N_EDGES);
    wt_kernel<<<(IN_F * OUT_F + 255) / 256, 256, 0, stream>>>(weight, Wt);
    gemm_mfma_kernel<<<(N_NODES + 63) / 64, 256, 0, stream>>>(feat, Wt, deg_out, h, N_NODES);
    gather_kernel<<<(N_NODES + 3) / 4, 256, 0, stream>>>(h, ed, row_ptr, out, N_NODES);
}

// Round 5
// 492.912 us; speedup vs baseline: 6.2503x; 1.0883x over previous
//
#include <hip/hip_runtime.h>
#include <hip/hip_fp16.h>
#include <math.h>

#define N_NODES 100000
#define N_EDGES 1600000
#define IN_F 256
#define OUT_F 128
#define SCAN_TPB 256
#define SCAN_EPB 1024

// hist partition: R node ranges x C edge chunks
#define HR 8
#define HRANGE 12500          // 100000 / 8  (LDS bins per block, 50 KB)
#define HC 32
#define HCHUNK 50000          // 1600000 / 32

typedef _Float16 h8 __attribute__((ext_vector_type(8)));
typedef float f4 __attribute__((ext_vector_type(4)));

// ---------------- LDS-privatized partitioned histogram ----------------
// grid = 2(type) x HR x HC = 512 blocks. type 0: dst histogram (+ per-edge
// local rank), type 1: src histogram. No global atomics anywhere.
__global__ __launch_bounds__(256) void hist_kernel(
        const int* __restrict__ src, const int* __restrict__ dst,
        int* __restrict__ rank, int* __restrict__ partial_in,
        int* __restrict__ partial_out) {
    __shared__ int bins[HRANGE];   // 50,000 B
    int b = blockIdx.x;
    int c = b >> 4;          // 0..31 chunk
    int tr = b & 15;
    int type = tr >> 3;      // 0 = dst, 1 = src
    int r = tr & 7;          // 0..7 range
    for (int i = threadIdx.x; i < HRANGE; i += 256) bins[i] = 0;
    __syncthreads();
    const int* nodes = type ? src : dst;
    int e0 = c * HCHUNK;
    int lo = r * HRANGE;
    for (int i = threadIdx.x; i < HCHUNK; i += 256) {
        int e = e0 + i;
        int node = nodes[e];
        unsigned loc = (unsigned)(node - lo);
        if (loc < (unsigned)HRANGE) {
            int rk = atomicAdd(&bins[loc], 1);
            if (type == 0) rank[e] = rk;
        }
    }
    __syncthreads();
    int* part = type ? partial_out : partial_in;
    for (int i = threadIdx.x; i < HRANGE; i += 256)
        part[c * N_NODES + lo + i] = bins[i];
}

// ---------------- deg_out[n] = sum_c partial_out[c][n] ----------------
__global__ __launch_bounds__(256) void reduce_out_kernel(
        const int* __restrict__ partial_out, int* __restrict__ deg_out, int N) {
    int n = blockIdx.x * 256 + threadIdx.x;
    if (n < N) {
        int s = 0;
        #pragma unroll
        for (int c = 0; c < HC; ++c) s += partial_out[c * N_NODES + n];
        deg_out[n] = s;
    }
}

// ---------------- deg_in + per-chunk exclusive bases ----------------
__global__ __launch_bounds__(256) void reduce_in_kernel(
        const int* __restrict__ partial_in, int* __restrict__ chunk_base,
        int* __restrict__ deg_in, int N) {
    int n = blockIdx.x * 256 + threadIdx.x;
    if (n < N) {
        int run = 0;
        #pragma unroll
        for (int c = 0; c < HC; ++c) {
            int v = partial_in[c * N_NODES + n];
            chunk_base[c * N_NODES + n] = run;
            run += v;
        }
        deg_in[n] = run;
    }
}

// ---------------- 3-kernel multi-block exclusive scan of deg_in ----------------
__global__ __launch_bounds__(SCAN_TPB) void scan_part1(const int* __restrict__ deg,
                                                       int* __restrict__ partials, int N) {
    __shared__ int tmp[SCAN_TPB];
    int t = threadIdx.x;
    int i0 = blockIdx.x * SCAN_EPB + t * 4;
    int s = 0;
    #pragma unroll
    for (int j = 0; j < 4; ++j) s += (i0 + j < N) ? deg[i0 + j] : 0;
    tmp[t] = s;
    __syncthreads();
    for (int off = SCAN_TPB / 2; off > 0; off >>= 1) {
        if (t < off) tmp[t] += tmp[t + off];
        __syncthreads();
    }
    if (t == 0) partials[blockIdx.x] = tmp[0];
}

__global__ __launch_bounds__(128) void scan_part2(const int* __restrict__ partials,
                                                  int* __restrict__ bases, int nb) {
    __shared__ int tmp[128];
    int t = threadIdx.x;
    int v = (t < nb) ? partials[t] : 0;
    tmp[t] = v;
    __syncthreads();
    int x = v;
    for (int off = 1; off < 128; off <<= 1) {
        int y = (t >= off) ? tmp[t - off] : 0;
        __syncthreads();
        x += y;
        tmp[t] = x;
        __syncthreads();
    }
    if (t < nb) bases[t] = x - v;   // exclusive
}

__global__ __launch_bounds__(SCAN_TPB) void scan_part3(const int* __restrict__ deg,
                                                       const int* __restrict__ bases,
                                                       int* __restrict__ row_ptr, int N) {
    __shared__ int tmp[SCAN_TPB];
    int t = threadIdx.x;
    int i0 = blockIdx.x * SCAN_EPB + t * 4;
    int v[4];
    int s = 0;
    #pragma unroll
    for (int j = 0; j < 4; ++j) { v[j] = (i0 + j < N) ? deg[i0 + j] : 0; s += v[j]; }
    tmp[t] = s;
    __syncthreads();
    int x = s;
    for (int off = 1; off < SCAN_TPB; off <<= 1) {
        int y = (t >= off) ? tmp[t - off] : 0;
        __syncthreads();
        x += y;
        tmp[t] = x;
        __syncthreads();
    }
    int excl = bases[blockIdx.x] + x - s;
    #pragma unroll
    for (int j = 0; j < 4; ++j) {
        if (i0 + j < N) row_ptr[i0 + j] = excl;
        excl += v[j];
    }
    if (blockIdx.x == gridDim.x - 1 && t == SCAN_TPB - 1) row_ptr[N] = bases[blockIdx.x] + x;
}

// ---------------- atomic-free fill: dst-grouped packed (src, ew) ----------------
__global__ void fill_kernel(const int* __restrict__ src,
                            const int* __restrict__ dst,
                            const float* __restrict__ ew,
                            const int* __restrict__ row_ptr,
                            const int* __restrict__ chunk_base,
                            const int* __restrict__ rank,
                            int2* __restrict__ ed, int E) {
    int e = blockIdx.x * blockDim.x + threadIdx.x;
    if (e < E) {
        int d = dst[e];
        int c = e / HCHUNK;
        int p = row_ptr[d] + chunk_base[c * N_NODES + d] + rank[e];
        ed[p] = make_int2(src[e], __float_as_int(ew[e]));
    }
}

// ---------------- Wt[n][k] = (f16) W[k][n] ----------------
__global__ void wt_kernel(const float* __restrict__ W, _Float16* __restrict__ Wt) {
    int i = blockIdx.x * blockDim.x + threadIdx.x;
    if (i < IN_F * OUT_F) {
        int n = i >> 8;
        int k = i & 255;
        Wt[i] = (_Float16)W[k * OUT_F + n];
    }
}

// ---------------- h = tanh((feat * rsqrt(out_deg)) @ W), f16 MFMA ----------------
__global__ __launch_bounds__(256) void gemm_mfma_kernel(
        const float* __restrict__ feat, const _Float16* __restrict__ Wt,
        const int* __restrict__ deg_out, __half* __restrict__ h, int N) {
    const int wave = threadIdx.x >> 6;
    const int lane = threadIdx.x & 63;
    const int m = lane & 15;
    const int quad = lane >> 4;
    const int rowbase = blockIdx.x * 64 + wave * 16;
    const int arow = rowbase + m;
    const bool rowok = arow < N;

    float rs = 1.f;
    if (rowok) {
        int dg = deg_out[arow]; if (dg < 1) dg = 1;
        rs = rsqrtf((float)dg);
    }
    const float* ap = feat + (size_t)(rowok ? arow : 0) * IN_F + quad * 8;

    f4 acc[8];
    #pragma unroll
    for (int t = 0; t < 8; ++t) acc[t] = (f4){0.f, 0.f, 0.f, 0.f};

    #pragma unroll
    for (int k0 = 0; k0 < IN_F; k0 += 32) {
        float4 f0 = make_float4(0.f, 0.f, 0.f, 0.f);
        float4 f1 = make_float4(0.f, 0.f, 0.f, 0.f);
        if (rowok) {
            f0 = *(const float4*)(ap + k0);
            f1 = *(const float4*)(ap + k0 + 4);
        }
        h8 a;
        a[0] = (_Float16)(f0.x * rs); a[1] = (_Float16)(f0.y * rs);
        a[2] = (_Float16)(f0.z * rs); a[3] = (_Float16)(f0.w * rs);
        a[4] = (_Float16)(f1.x * rs); a[5] = (_Float16)(f1.y * rs);
        a[6] = (_Float16)(f1.z * rs); a[7] = (_Float16)(f1.w * rs);
        const int k = k0 + quad * 8;
        #pragma unroll
        for (int t = 0; t < 8; ++t) {
            h8 b = *(const h8*)&Wt[(size_t)(t * 16 + m) * IN_F + k];
            acc[t] = __builtin_amdgcn_mfma_f32_16x16x32_f16(a, b, acc[t], 0, 0, 0);
        }
    }

    const int crow0 = rowbase + quad * 4;
    #pragma unroll
    for (int t = 0; t < 8; ++t) {
        #pragma unroll
        for (int r = 0; r < 4; ++r) {
            int rr = crow0 + r;
            if (rr < N) h[(size_t)rr * OUT_F + t * 16 + m] = __float2half(tanhf(acc[t][r]));
        }
    }
}

// ---------------- gather: one wave per dst node, 4 edges/instr, unroll 2 ----------------
__global__ __launch_bounds__(256) void gather_kernel(
        const __half* __restrict__ h, const int2* __restrict__ ed,
        const int* __restrict__ row_ptr, float* __restrict__ out, int N) {
    int wave = threadIdx.x >> 6;
    int lane = threadIdx.x & 63;
    int node = blockIdx.x * 4 + wave;
    if (node >= N) return;
    int lo = row_ptr[node];
    int hi = row_ptr[node + 1];
    int p = lane >> 4;       // edge slot 0..3
    int c = lane & 15;       // feature octet: feats 8c..8c+7
    float4 a0 = make_float4(0.f, 0.f, 0.f, 0.f);
    float4 a1 = make_float4(0.f, 0.f, 0.f, 0.f);
    float4 b0 = make_float4(0.f, 0.f, 0.f, 0.f);
    float4 b1 = make_float4(0.f, 0.f, 0.f, 0.f);
    for (int j = lo; j < hi; j += 8) {
        int ja = j + p;
        int jb = j + 4 + p;
        int2 ea = (ja < hi) ? ed[ja] : make_int2(0, 0);
        int2 eb = (jb < hi) ? ed[jb] : make_int2(0, 0);
        float wa = __int_as_float(ea.y);
        float wb = __int_as_float(eb.y);
        int4 ra = *(const int4*)(h + (size_t)ea.x * OUT_F + c * 8);
        int4 rb = *(const int4*)(h + (size_t)eb.x * OUT_F + c * 8);
        float2 t;
        t = __half22float2(*(__half2*)&ra.x); a0.x += wa * t.x; a0.y += wa * t.y;
        t = __half22float2(*(__half2*)&ra.y); a0.z += wa * t.x; a0.w += wa * t.y;
        t = __half22float2(*(__half2*)&ra.z); a1.x += wa * t.x; a1.y += wa * t.y;
        t = __half22float2(*(__half2*)&ra.w); a1.z += wa * t.x; a1.w += wa * t.y;
        t = __half22float2(*(__half2*)&rb.x); b0.x += wb * t.x; b0.y += wb * t.y;
        t = __half22float2(*(__half2*)&rb.y); b0.z += wb * t.x; b0.w += wb * t.y;
        t = __half22float2(*(__half2*)&rb.z); b1.x += wb * t.x; b1.y += wb * t.y;
        t = __half22float2(*(__half2*)&rb.w); b1.z += wb * t.x; b1.w += wb * t.y;
    }
    a0.x += b0.x; a0.y += b0.y; a0.z += b0.z; a0.w += b0.w;
    a1.x += b1.x; a1.y += b1.y; a1.z += b1.z; a1.w += b1.w;
    float v[8] = {a0.x, a0.y, a0.z, a0.w, a1.x, a1.y, a1.z, a1.w};
    #pragma unroll
    for (int i = 0; i < 8; ++i) {
        v[i] += __shfl_xor(v[i], 16);
        v[i] += __shfl_xor(v[i], 32);
    }
    if (p == 0) {
        int deg = hi - lo; if (deg < 1) deg = 1;
        float rs = rsqrtf((float)deg);
        float* op = out + (size_t)node * OUT_F + c * 8;
        *(float4*)op       = make_float4(v[0] * rs, v[1] * rs, v[2] * rs, v[3] * rs);
        *(float4*)(op + 4) = make_float4(v[4] * rs, v[5] * rs, v[6] * rs, v[7] * rs);
    }
}

extern "C" void kernel_launch(void* const* d_in, const int* in_sizes, int n_in,
                              void* d_out, int out_size, void* d_ws, size_t ws_size,
                              hipStream_t stream) {
    const float* feat   = (const float*)d_in[0];
    const float* weight = (const float*)d_in[1];
    const float* ew     = (const float*)d_in[2];
    const int*   src    = (const int*)d_in[3];
    const int*   dst    = (const int*)d_in[4];
    float* out = (float*)d_out;

    // workspace layout (aliased regions; total 58,867,600 B <= proven budget)
    char* ws = (char*)d_ws;
    int* deg_out    = (int*)(ws);                   // 400,000
    int* deg_in     = (int*)(ws + 400000);          // 400,000
    int* row_ptr    = (int*)(ws + 800000);          // 400,016
    int* spart      = (int*)(ws + 1200016);         // 1,024
    int* sbases     = (int*)(ws + 1201040);         // 1,024
    int* rank       = (int*)(ws + 1202064);         // 6,400,000
    int* partial_in = (int*)(ws + 7602064);         // 12,800,000 (aliased by ed)
    int2* ed        = (int2*)(ws + 7602064);
    int* partial_out = (int*)(ws + 20402064);       // 12,800,000 (aliased by chunk_base)
    int* chunk_base  = (int*)(ws + 20402064);
    __half* h       = (__half*)(ws + 33202064);     // 25,600,000
    _Float16* Wt    = (_Float16*)(ws + 58802064);   // 65,536

    const int nb = (N_NODES + SCAN_EPB - 1) / SCAN_EPB;   // 98

    hist_kernel<<<2 * HR * HC, 256, 0, stream>>>(src, dst, rank, partial_in, partial_out);
    reduce_out_kernel<<<(N_NODES + 255) / 256, 256, 0, stream>>>(partial_out, deg_out, N_NODES);
    reduce_in_kernel<<<(N_NODES + 255) / 256, 256, 0, stream>>>(partial_in, chunk_base, deg_in, N_NODES);
    scan_part1<<<nb, SCAN_TPB, 0, stream>>>(deg_in, spart, N_NODES);
    scan_part2<<<1, 128, 0, stream>>>(spart, sbases, nb);
    scan_part3<<<nb, SCAN_TPB, 0, stream>>>(deg_in, sbases, row_ptr, N_NODES);
    // fill overwrites the partial_in region (ed) while reading chunk_base
    // (old partial_out region) — both partials are dead by now.
    fill_kernel<<<(N_EDGES + 255) / 256, 256, 0, stream>>>(src, dst, ew, row_ptr,
                                                           chunk_base, rank, ed, N_EDGES);
    wt_kernel<<<(IN_F * OUT_F + 255) / 256, 256, 0, stream>>>(weight, Wt);
    gemm_mfma_kernel<<<(N_NODES + 63) / 64, 256, 0, stream>>>(feat, Wt, deg_out, h, N_NODES);
    gather_kernel<<<(N_NODES + 3) / 4, 256, 0, stream>>>(h, ed, row_ptr, out, N_NODES);
}

// Round 6
// 412.419 us; speedup vs baseline: 7.4701x; 1.1952x over previous
//
#include <hip/hip_runtime.h>
#include <hip/hip_fp16.h>
#include <math.h>

#define N_NODES 100000
#define N_EDGES 1600000
#define IN_F 256
#define OUT_F 128
#define SCAN_TPB 256
#define SCAN_EPB 1024

// hist partition: R node ranges x C edge chunks, packed 16-bit LDS bins
#define HR 4
#define HRANGE 25000          // nodes per range (50 KB LDS as packed u16)
#define HC 64
#define HCHUNK 25000          // edges per chunk (divisible by 4)
#define PWORDS (N_NODES / 2)  // packed words per chunk row (50,000)

typedef _Float16 h8 __attribute__((ext_vector_type(8)));
typedef float f4 __attribute__((ext_vector_type(4)));

// ---------------- LDS-privatized histogram, packed 16-bit bins ----------------
// grid = HC x (2 type x HR) = 512 blocks. type 0: dst (+ per-edge rank),
// type 1: src. Counts per (chunk,node) < 25000 so 16-bit halves never overflow.
__global__ __launch_bounds__(256) void hist_kernel(
        const int* __restrict__ src, const int* __restrict__ dst,
        int* __restrict__ rank, unsigned int* __restrict__ partial_in,
        unsigned int* __restrict__ partial_out) {
    __shared__ unsigned int bins[HRANGE / 2];   // 50,000 B
    int b = blockIdx.x;
    int c = b >> 3;          // 0..63 chunk
    int tr = b & 7;
    int type = tr >> 2;      // 0 = dst, 1 = src
    int r = tr & 3;          // 0..3 range
    for (int i = threadIdx.x; i < HRANGE / 2; i += 256) bins[i] = 0;
    __syncthreads();
    const int* nodes = type ? src : dst;
    const int e0 = c * HCHUNK;
    const int lo = r * HRANGE;
    const int ngroups = HCHUNK / 4;   // 6250
    for (int g = threadIdx.x; g < ngroups; g += 256) {
        int e = e0 + g * 4;
        int4 n4 = *(const int4*)(nodes + e);
        int nn[4] = {n4.x, n4.y, n4.z, n4.w};
        #pragma unroll
        for (int j = 0; j < 4; ++j) {
            unsigned loc = (unsigned)(nn[j] - lo);
            if (loc < (unsigned)HRANGE) {
                unsigned sh = (loc & 1) * 16;
                unsigned old = atomicAdd(&bins[loc >> 1], 1u << sh);
                if (type == 0) rank[e + j] = (int)((old >> sh) & 0xffffu);
            }
        }
    }
    __syncthreads();
    unsigned int* part = type ? partial_out : partial_in;
    unsigned int* dstp = part + (size_t)c * PWORDS + (lo >> 1);
    for (int i = threadIdx.x; i < HRANGE / 2; i += 256) dstp[i] = bins[i];
}

// ---------------- fused reduce: deg_in + chunk_base16 + rs_out + scan partials ----------------
// block = 256 threads x 4 nodes = 1024 nodes (matches SCAN_EPB)
__global__ __launch_bounds__(256) void fused_reduce_kernel(
        const unsigned int* __restrict__ partial_in,
        const unsigned int* __restrict__ partial_out,
        unsigned short* __restrict__ chunk_base16,
        int* __restrict__ deg_in, float* __restrict__ rs_out,
        int* __restrict__ spart, int N) {
    __shared__ int tmp[256];
    int t = threadIdx.x;
    int n0 = blockIdx.x * SCAN_EPB + t * 4;
    int run[4] = {0, 0, 0, 0};
    int sout[4] = {0, 0, 0, 0};
    if (n0 < N) {
        const int w0 = n0 >> 1;    // word offset (n0 multiple of 4 -> even)
        #pragma unroll 4
        for (int c = 0; c < HC; ++c) {
            // chunk_base = running sum of per-chunk dst counts
            ushort4 cb;
            cb.x = (unsigned short)run[0]; cb.y = (unsigned short)run[1];
            cb.z = (unsigned short)run[2]; cb.w = (unsigned short)run[3];
            *(ushort4*)(chunk_base16 + (size_t)c * N_NODES + n0) = cb;
            uint2 pi = *(const uint2*)(partial_in + (size_t)c * PWORDS + w0);
            run[0] += (int)(pi.x & 0xffffu);  run[1] += (int)(pi.x >> 16);
            run[2] += (int)(pi.y & 0xffffu);  run[3] += (int)(pi.y >> 16);
            uint2 po = *(const uint2*)(partial_out + (size_t)c * PWORDS + w0);
            sout[0] += (int)(po.x & 0xffffu); sout[1] += (int)(po.x >> 16);
            sout[2] += (int)(po.y & 0xffffu); sout[3] += (int)(po.y >> 16);
        }
        *(int4*)(deg_in + n0) = make_int4(run[0], run[1], run[2], run[3]);
        float4 rs;
        rs.x = rsqrtf((float)(sout[0] < 1 ? 1 : sout[0]));
        rs.y = rsqrtf((float)(sout[1] < 1 ? 1 : sout[1]));
        rs.z = rsqrtf((float)(sout[2] < 1 ? 1 : sout[2]));
        rs.w = rsqrtf((float)(sout[3] < 1 ? 1 : sout[3]));
        *(float4*)(rs_out + n0) = rs;
    }
    tmp[t] = run[0] + run[1] + run[2] + run[3];
    __syncthreads();
    for (int off = 128; off > 0; off >>= 1) {
        if (t < off) tmp[t] += tmp[t + off];
        __syncthreads();
    }
    if (t == 0) spart[blockIdx.x] = tmp[0];
}

// ---------------- scan over block partials + final row_ptr ----------------
__global__ __launch_bounds__(128) void scan_part2(const int* __restrict__ partials,
                                                  int* __restrict__ bases, int nb) {
    __shared__ int tmp[128];
    int t = threadIdx.x;
    int v = (t < nb) ? partials[t] : 0;
    tmp[t] = v;
    __syncthreads();
    int x = v;
    for (int off = 1; off < 128; off <<= 1) {
        int y = (t >= off) ? tmp[t - off] : 0;
        __syncthreads();
        x += y;
        tmp[t] = x;
        __syncthreads();
    }
    if (t < nb) bases[t] = x - v;   // exclusive
}

__global__ __launch_bounds__(SCAN_TPB) void scan_part3(const int* __restrict__ deg,
                                                       const int* __restrict__ bases,
                                                       int* __restrict__ row_ptr, int N) {
    __shared__ int tmp[SCAN_TPB];
    int t = threadIdx.x;
    int i0 = blockIdx.x * SCAN_EPB + t * 4;
    int v[4];
    int s = 0;
    #pragma unroll
    for (int j = 0; j < 4; ++j) { v[j] = (i0 + j < N) ? deg[i0 + j] : 0; s += v[j]; }
    tmp[t] = s;
    __syncthreads();
    int x = s;
    for (int off = 1; off < SCAN_TPB; off <<= 1) {
        int y = (t >= off) ? tmp[t - off] : 0;
        __syncthreads();
        x += y;
        tmp[t] = x;
        __syncthreads();
    }
    int excl = bases[blockIdx.x] + x - s;
    #pragma unroll
    for (int j = 0; j < 4; ++j) {
        if (i0 + j < N) row_ptr[i0 + j] = excl;
        excl += v[j];
    }
    if (blockIdx.x == gridDim.x - 1 && t == SCAN_TPB - 1) row_ptr[N] = bases[blockIdx.x] + x;
}

// ---------------- atomic-free fill: dst-grouped packed (src, ew), int4 loads ----------------
__global__ __launch_bounds__(256) void fill_kernel(
        const int* __restrict__ src, const int* __restrict__ dst,
        const float* __restrict__ ew, const int* __restrict__ row_ptr,
        const unsigned short* __restrict__ chunk_base16,
        const int* __restrict__ rank, int2* __restrict__ ed, int E) {
    int e0 = (blockIdx.x * 256 + threadIdx.x) * 4;
    if (e0 >= E) return;
    int4 s4 = *(const int4*)(src + e0);
    int4 d4 = *(const int4*)(dst + e0);
    float4 w4 = *(const float4*)(ew + e0);
    int4 r4 = *(const int4*)(rank + e0);
    int c = e0 / HCHUNK;   // groups never straddle chunks (HCHUNK % 4 == 0)
    const unsigned short* cb = chunk_base16 + (size_t)c * N_NODES;
    int dd[4] = {d4.x, d4.y, d4.z, d4.w};
    int ss[4] = {s4.x, s4.y, s4.z, s4.w};
    int rr[4] = {r4.x, r4.y, r4.z, r4.w};
    float ww[4] = {w4.x, w4.y, w4.z, w4.w};
    #pragma unroll
    for (int j = 0; j < 4; ++j) {
        int d = dd[j];
        int p = row_ptr[d] + (int)cb[d] + rr[j];
        unsigned long long v = (unsigned long long)(unsigned int)ss[j] |
                               ((unsigned long long)(unsigned int)__float_as_int(ww[j]) << 32);
        __builtin_nontemporal_store(v, (unsigned long long*)&ed[p]);
    }
}

// ---------------- Wt[n][k] = (f16) W[k][n] ----------------
__global__ void wt_kernel(const float* __restrict__ W, _Float16* __restrict__ Wt) {
    int i = blockIdx.x * blockDim.x + threadIdx.x;
    if (i < IN_F * OUT_F) {
        int n = i >> 8;
        int k = i & 255;
        Wt[i] = (_Float16)W[k * OUT_F + n];
    }
}

// ---------------- h = tanh((feat * rs_out[row]) @ W), f16 MFMA ----------------
__global__ __launch_bounds__(256) void gemm_mfma_kernel(
        const float* __restrict__ feat, const _Float16* __restrict__ Wt,
        const float* __restrict__ rs_out, __half* __restrict__ h, int N) {
    const int wave = threadIdx.x >> 6;
    const int lane = threadIdx.x & 63;
    const int m = lane & 15;
    const int quad = lane >> 4;
    const int rowbase = blockIdx.x * 64 + wave * 16;
    const int arow = rowbase + m;
    const bool rowok = arow < N;

    const float rs = rowok ? rs_out[arow] : 1.f;
    const float* ap = feat + (size_t)(rowok ? arow : 0) * IN_F + quad * 8;

    f4 acc[8];
    #pragma unroll
    for (int t = 0; t < 8; ++t) acc[t] = (f4){0.f, 0.f, 0.f, 0.f};

    #pragma unroll
    for (int k0 = 0; k0 < IN_F; k0 += 32) {
        float4 f0 = make_float4(0.f, 0.f, 0.f, 0.f);
        float4 f1 = make_float4(0.f, 0.f, 0.f, 0.f);
        if (rowok) {
            f0 = *(const float4*)(ap + k0);
            f1 = *(const float4*)(ap + k0 + 4);
        }
        h8 a;
        a[0] = (_Float16)(f0.x * rs); a[1] = (_Float16)(f0.y * rs);
        a[2] = (_Float16)(f0.z * rs); a[3] = (_Float16)(f0.w * rs);
        a[4] = (_Float16)(f1.x * rs); a[5] = (_Float16)(f1.y * rs);
        a[6] = (_Float16)(f1.z * rs); a[7] = (_Float16)(f1.w * rs);
        const int k = k0 + quad * 8;
        #pragma unroll
        for (int t = 0; t < 8; ++t) {
            h8 b = *(const h8*)&Wt[(size_t)(t * 16 + m) * IN_F + k];
            acc[t] = __builtin_amdgcn_mfma_f32_16x16x32_f16(a, b, acc[t], 0, 0, 0);
        }
    }

    const int crow0 = rowbase + quad * 4;
    #pragma unroll
    for (int t = 0; t < 8; ++t) {
        #pragma unroll
        for (int r = 0; r < 4; ++r) {
            int rr = crow0 + r;
            if (rr < N) h[(size_t)rr * OUT_F + t * 16 + m] = __float2half(tanhf(acc[t][r]));
        }
    }
}

// ---------------- gather: one wave per dst node, 4 edge-slots x 4-deep unroll ----------------
__global__ __launch_bounds__(256) void gather_kernel(
        const __half* __restrict__ h, const int2* __restrict__ ed,
        const int* __restrict__ row_ptr, float* __restrict__ out, int N) {
    int wave = threadIdx.x >> 6;
    int lane = threadIdx.x & 63;
    int node = blockIdx.x * 4 + wave;
    if (node >= N) return;
    int lo = row_ptr[node];
    int hi = row_ptr[node + 1];
    int p = lane >> 4;       // edge slot 0..3
    int c = lane & 15;       // feature octet: feats 8c..8c+7
    float acc[4][8];
    #pragma unroll
    for (int g = 0; g < 4; ++g)
        #pragma unroll
        for (int i = 0; i < 8; ++i) acc[g][i] = 0.f;

    for (int j = lo; j < hi; j += 16) {
        #pragma unroll
        for (int g = 0; g < 4; ++g) {
            int jj = j + g * 4 + p;
            int2 e = (jj < hi) ? ed[jj] : make_int2(0, 0);
            float w = __int_as_float(e.y);
            int4 rrow = *(const int4*)(h + (size_t)e.x * OUT_F + c * 8);
            float2 t;
            t = __half22float2(*(__half2*)&rrow.x); acc[g][0] += w * t.x; acc[g][1] += w * t.y;
            t = __half22float2(*(__half2*)&rrow.y); acc[g][2] += w * t.x; acc[g][3] += w * t.y;
            t = __half22float2(*(__half2*)&rrow.z); acc[g][4] += w * t.x; acc[g][5] += w * t.y;
            t = __half22float2(*(__half2*)&rrow.w); acc[g][6] += w * t.x; acc[g][7] += w * t.y;
        }
    }
    float v[8];
    #pragma unroll
    for (int i = 0; i < 8; ++i) {
        v[i] = (acc[0][i] + acc[1][i]) + (acc[2][i] + acc[3][i]);
        v[i] += __shfl_xor(v[i], 16);
        v[i] += __shfl_xor(v[i], 32);
    }
    if (p == 0) {
        int deg = hi - lo; if (deg < 1) deg = 1;
        float rs = rsqrtf((float)deg);
        float* op = out + (size_t)node * OUT_F + c * 8;
        *(float4*)op       = make_float4(v[0] * rs, v[1] * rs, v[2] * rs, v[3] * rs);
        *(float4*)(op + 4) = make_float4(v[4] * rs, v[5] * rs, v[6] * rs, v[7] * rs);
    }
}

extern "C" void kernel_launch(void* const* d_in, const int* in_sizes, int n_in,
                              void* d_out, int out_size, void* d_ws, size_t ws_size,
                              hipStream_t stream) {
    const float* feat   = (const float*)d_in[0];
    const float* weight = (const float*)d_in[1];
    const float* ew     = (const float*)d_in[2];
    const int*   src    = (const int*)d_in[3];
    const int*   dst    = (const int*)d_in[4];
    float* out = (float*)d_out;

    // workspace layout with aliasing (total 46.07 MB):
    //   ed (12.8M)  overlays partial_in  (dead after fused_reduce)
    //   h  (25.6M)  overlays chunk_base16 + partial_out (dead after fill/reduce)
    char* ws = (char*)d_ws;
    float* rs_out      = (float*)(ws);                       // 400,000
    int*   deg_in      = (int*)(ws + 400000);                // 400,000
    int*   row_ptr     = (int*)(ws + 800000);                // 400,016
    int*   spart       = (int*)(ws + 1200016);               // 512
    int*   sbases      = (int*)(ws + 1200528);               // 512
    int*   rank        = (int*)(ws + 1201056);               // 6,400,000
    unsigned int* partial_in  = (unsigned int*)(ws + 7601056);   // 12,800,000
    int2*  ed          = (int2*)(ws + 7601056);                  // alias ^
    unsigned short* chunk_base16 = (unsigned short*)(ws + 20401056); // 12,800,000
    unsigned int* partial_out = (unsigned int*)(ws + 33201056);  // 12,800,000
    __half* h          = (__half*)(ws + 20401056);               // alias of cb16+p_out
    _Float16* Wt       = (_Float16*)(ws + 46001056);             // 65,536

    const int nb = (N_NODES + SCAN_EPB - 1) / SCAN_EPB;   // 98

    hist_kernel<<<2 * HR * HC, 256, 0, stream>>>(src, dst, rank, partial_in, partial_out);
    fused_reduce_kernel<<<nb, 256, 0, stream>>>(partial_in, partial_out, chunk_base16,
                                                deg_in, rs_out, spart, N_NODES);
    scan_part2<<<1, 128, 0, stream>>>(spart, sbases, nb);
    scan_part3<<<nb, SCAN_TPB, 0, stream>>>(deg_in, sbases, row_ptr, N_NODES);
    fill_kernel<<<(N_EDGES / 4 + 255) / 256, 256, 0, stream>>>(src, dst, ew, row_ptr,
                                                               chunk_base16, rank, ed, N_EDGES);
    wt_kernel<<<(IN_F * OUT_F + 255) / 256, 256, 0, stream>>>(weight, Wt);
    gemm_mfma_kernel<<<(N_NODES + 63) / 64, 256, 0, stream>>>(feat, Wt, rs_out, h, N_NODES);
    gather_kernel<<<(N_NODES + 3) / 4, 256, 0, stream>>>(h, ed, row_ptr, out, N_NODES);
}